// Round 3
// baseline (956.215 us; speedup 1.0000x reference)
//
#include <hip/hip_runtime.h>

// FeatureDecoder: 4x (Linear -> BN(batch stats) -> ReLU -> Linear) with gathers.
// R5: deepen A-prefetch to 2 K-tiles ahead (HBM-latency was the R4 bottleneck:
// 1.9 TB/s with MfmaUtil 25% = latency-bound, loads had only ~500cy slack).
// Non-AFFINE: A 3-slot rotation (gld_lds, issued at PH2/PH3 of t for tile t+2,
// confirmed VMCNT(6) end of t+1 -> ~6 phases slack); B single slot (L2-hot
// stream, 1-ahead, read/overwrite race closed by LGKM0-before-BAR + post-BAR
// issue). AFFINE: A double-slot ds_write 1-ahead from double reg-sets loaded
// 2-ahead (2-unrolled loop keeps set indexing static). Same T2 swizzle (0 bank
// conflicts in R4) + T5 setprio. Ledger: steady VMCNT(4)@PH0 / VMCNT(6)@PH3,
// peel VMCNT(2)/(0).

typedef unsigned short u16;
typedef __attribute__((ext_vector_type(8))) short bf16x8;
typedef __attribute__((ext_vector_type(4))) float f32x4;

#define UNROLL _Pragma("unroll")
#define EPW 264  // epilogue LDS row stride (u16)

__device__ __forceinline__ float b2f(u16 u) {
    union { unsigned int i; float f; } v; v.i = ((unsigned int)u) << 16; return v.f;
}
__device__ __forceinline__ u16 f2b(float f) {
    union { float f; unsigned int i; } v; v.f = f;
    unsigned int r = v.i + 0x7FFFu + ((v.i >> 16) & 1u);
    return (u16)(r >> 16);
}

__device__ __forceinline__ void gld_lds16(const u16* g, u16* l) {
    __builtin_amdgcn_global_load_lds(
        (const __attribute__((address_space(1))) unsigned int*)g,
        (__attribute__((address_space(3))) unsigned int*)l,
        16, 0, 0);
}

#define VMCNT(n) asm volatile("s_waitcnt vmcnt(" #n ")" ::: "memory")
#define LGKM0    asm volatile("s_waitcnt lgkmcnt(0)" ::: "memory")
#define BAR()    do{ asm volatile("" ::: "memory"); \
                     __builtin_amdgcn_s_barrier(); \
                     asm volatile("" ::: "memory"); }while(0)

union SMem {
    struct { u16 a[3][16384]; u16 b[16384]; } g;                      // 131072 B
    struct { u16 a[2][16384]; u16 b[2][16384]; float ss[2048]; } f;   // 139264 B
    u16 ep[256 * EPW];                                                 // 135168 B
};

// ---------------- GEMM: C(MxN) = A(MxK bf16) @ BT(NxK bf16)^T ----------------
template <bool AFFINE_A, bool STATS, bool OUT_F32, bool GATHER>
__global__ __launch_bounds__(512, 2) void gemm_bn(
    const u16* __restrict__ A, const u16* __restrict__ BT, void* __restrict__ Cout,
    const float* __restrict__ scale, const float* __restrict__ shift,
    const float* __restrict__ bias,
    float* __restrict__ psum, float* __restrict__ psumsq,
    const u16* __restrict__ Xg, const int* __restrict__ pool,
    int nfShift, int Nc, int Chalf,
    int N, int K)
{
    __shared__ __align__(16) SMem sm;

    const int tid  = threadIdx.x;
    const int w    = tid >> 6;
    const int lane = tid & 63;
    const int wm   = w >> 2, wn = w & 3;      // 2M x 4N waves; per-wave C = 128x64
    const int l15  = lane & 15;
    const int xorv = (lane & 7) << 3;          // read-side swizzle (row&7 == lane&7)
    const int swz8 = ((lane & 7) ^ (lane >> 3)) << 3;  // write-source swizzle chunk
    const int kS0  = (((lane >> 4) << 3)) ^ xorv;
    const int kS1  = (32 + ((lane >> 4) << 3)) ^ xorv;

    // XCD-aware bijective swizzle (all grids are %8==0): contiguous chunk per XCD.
    int bm, bn;
    {
        const int nbn  = (int)gridDim.x;
        const int nwg  = nbn * (int)gridDim.y;
        const int flat = (int)(blockIdx.y * gridDim.x + blockIdx.x);
        const int wg   = (flat & 7) * (nwg >> 3) + (flat >> 3);
        const int lb   = 31 - __builtin_clz(nbn);
        bn = wg & (nbn - 1);
        bm = wg >> lb;
    }

    // ---- staging source/dest setup ----
    const u16* aS[2][2]; const u16* xS[2][2]; const u16* bS[2][2];
    int dA[2][2], dB[2][2], wIdx[2][2];
    UNROLL for (int u = 0; u < 2; u++)
    UNROLL for (int ld = 0; ld < 2; ld++) {
        const int urb = w * 16 + ld * 8;          // wave-uniform 8-row chunk base
        const int ur  = urb + (lane >> 3);        // per-lane unit-row
        {
            const int trb = urb + (urb >= 64 ? 64 : 0) + u * 64;
            const int tr  = ur  + (ur  >= 64 ? 64 : 0) + u * 64;
            dA[u][ld] = trb * 64;
            const int rowG = bm * 256 + tr;
            if constexpr (GATHER) {
                const int b = rowG >> nfShift;
                const int p = pool[rowG];
                aS[u][ld] = A  + (size_t)rowG * Chalf + swz8;
                xS[u][ld] = Xg + ((size_t)b * Nc + p) * Chalf + swz8;
            } else if constexpr (AFFINE_A) {
                aS[u][ld] = A + (size_t)rowG * K + ((lane & 7) << 3);  // linear src
                wIdx[u][ld] = tr * 64 + swz8;                          // swizzled dst
            } else {
                aS[u][ld] = A + (size_t)rowG * K + swz8;
            }
        }
        {
            const int trb = ((urb >> 5) << 6) + (urb & 31) + u * 32;
            const int tr  = ((ur  >> 5) << 6) + (ur  & 31) + u * 32;
            dB[u][ld] = trb * 64;
            bS[u][ld] = BT + (size_t)(bn * 256 + tr) * K + swz8;
        }
    }

    f32x4 acc[8][4];
    const f32x4 zero = {0.f, 0.f, 0.f, 0.f};
    UNROLL for (int i = 0; i < 8; i++)
    UNROLL for (int j = 0; j < 4; j++) acc[i][j] = zero;
    bf16x8 afr[4][2];
    bf16x8 bfr[2][2][2];
    uint4 rAe[2][2], rAo[2][2];   // AFFINE in-flight A reg sets (dead otherwise)

#define ABASE(T, RS) (AFFINE_A ? &sm.f.a[(T) & 1][0] : &sm.g.a[(RS)][0])
#define BRD(T)       (AFFINE_A ? &sm.f.b[(T) & 1][0] : &sm.g.b[0])
#define BSTG(TP)     (AFFINE_A ? &sm.f.b[(TP) & 1][0] : &sm.g.b[0])

#define GLD_B(u, TP, KOF) do{ \
    u16* bt_ = BSTG(TP); \
    gld_lds16(bS[u][0] + (KOF), bt_ + dB[u][0]); \
    gld_lds16(bS[u][1] + (KOF), bt_ + dB[u][1]); }while(0)

#define ISSUE_A(u, WS, KOF) do{ \
    u16* at_ = &sm.g.a[(WS)][0]; \
    if constexpr (GATHER) { \
        const u16 *s0_, *s1_; \
        if ((KOF) < Chalf) { s0_ = aS[u][0] + (KOF); s1_ = aS[u][1] + (KOF); } \
        else { s0_ = xS[u][0] + ((KOF) - Chalf); s1_ = xS[u][1] + ((KOF) - Chalf); } \
        gld_lds16(s0_, at_ + dA[u][0]); \
        gld_lds16(s1_, at_ + dA[u][1]); \
    } else { \
        gld_lds16(aS[u][0] + (KOF), at_ + dA[u][0]); \
        gld_lds16(aS[u][1] + (KOF), at_ + dA[u][1]); \
    } }while(0)

#define LOAD_RA(SET, u, KOF) do{ \
    SET[u][0] = *(const uint4*)(aS[u][0] + (KOF)); \
    SET[u][1] = *(const uint4*)(aS[u][1] + (KOF)); }while(0)

#define AFFW(SET, u, TP, KOF) do{ if constexpr (AFFINE_A) { \
    u16* at_ = &sm.f.a[(TP) & 1][0]; \
    const int kb_ = (KOF) + ((lane & 7) << 3); \
    const float4 sc0_ = *(const float4*)&sm.f.ss[kb_]; \
    const float4 sc1_ = *(const float4*)&sm.f.ss[kb_ + 4]; \
    const float4 sh0_ = *(const float4*)&sm.f.ss[1024 + kb_]; \
    const float4 sh1_ = *(const float4*)&sm.f.ss[1024 + kb_ + 4]; \
    UNROLL for (int ld_ = 0; ld_ < 2; ld_++) { \
        union { uint4 u4; u16 s[8]; } r_, o_; r_.u4 = SET[u][ld_]; \
        o_.s[0] = f2b(fmaxf(b2f(r_.s[0]) * sc0_.x + sh0_.x, 0.f)); \
        o_.s[1] = f2b(fmaxf(b2f(r_.s[1]) * sc0_.y + sh0_.y, 0.f)); \
        o_.s[2] = f2b(fmaxf(b2f(r_.s[2]) * sc0_.z + sh0_.z, 0.f)); \
        o_.s[3] = f2b(fmaxf(b2f(r_.s[3]) * sc0_.w + sh0_.w, 0.f)); \
        o_.s[4] = f2b(fmaxf(b2f(r_.s[4]) * sc1_.x + sh1_.x, 0.f)); \
        o_.s[5] = f2b(fmaxf(b2f(r_.s[5]) * sc1_.y + sh1_.y, 0.f)); \
        o_.s[6] = f2b(fmaxf(b2f(r_.s[6]) * sc1_.z + sh1_.z, 0.f)); \
        o_.s[7] = f2b(fmaxf(b2f(r_.s[7]) * sc1_.w + sh1_.w, 0.f)); \
        *(uint4*)&at_[wIdx[u][ld_]] = o_.u4; } \
    } }while(0)

#define READ_A(base, qi) do{ const u16* p_ = (base); \
    UNROLL for (int i_ = 0; i_ < 4; i_++) { \
        const int rb_ = (wm * 128 + ((qi) * 4 + i_) * 16 + l15) * 64; \
        afr[i_][0] = *(const bf16x8*)&p_[rb_ + kS0]; \
        afr[i_][1] = *(const bf16x8*)&p_[rb_ + kS1]; } }while(0)

#define READ_B(base, qj) do{ const u16* p_ = (base); \
    UNROLL for (int j_ = 0; j_ < 2; j_++) { \
        const int rb_ = (wn * 64 + ((qj) * 2 + j_) * 16 + l15) * 64; \
        bfr[qj][j_][0] = *(const bf16x8*)&p_[rb_ + kS0]; \
        bfr[qj][j_][1] = *(const bf16x8*)&p_[rb_ + kS1]; } }while(0)

#define MFMA_Q(qi, qj) do{ __builtin_amdgcn_s_setprio(1); \
    UNROLL for (int i_ = 0; i_ < 4; i_++) \
    UNROLL for (int j_ = 0; j_ < 2; j_++) { \
        acc[(qi)*4+i_][(qj)*2+j_] = __builtin_amdgcn_mfma_f32_16x16x32_bf16( \
            afr[i_][0], bfr[qj][j_][0], acc[(qi)*4+i_][(qj)*2+j_], 0, 0, 0); \
        acc[(qi)*4+i_][(qj)*2+j_] = __builtin_amdgcn_mfma_f32_16x16x32_bf16( \
            afr[i_][1], bfr[qj][j_][1], acc[(qi)*4+i_][(qj)*2+j_], 0, 0, 0); } \
    __builtin_amdgcn_s_setprio(0); }while(0)

// Steady K-step: compute tile T, stage B(T+1), stage/load A(T+2), write A(T+1) (AFFINE).
#define KSTEP(T, RS, WS, SW, SL) do{ \
    const int kofB_ = ((T) + 1) << 6, kofL_ = ((T) + 2) << 6; \
    const u16* aR_ = ABASE(T, RS); \
    const u16* bR_ = BRD(T); \
    /* PH0 */ \
    READ_A(aR_, 0); READ_B(bR_, 0); \
    if constexpr (!AFFINE_A) LGKM0; \
    VMCNT(4); BAR(); \
    GLD_B(0, (T) + 1, kofB_); \
    MFMA_Q(0, 0); \
    /* PH1 */ \
    READ_B(bR_, 1); \
    if constexpr (!AFFINE_A) LGKM0; \
    BAR(); \
    GLD_B(1, (T) + 1, kofB_); \
    MFMA_Q(0, 1); \
    /* PH2 */ \
    READ_A(aR_, 1); \
    if constexpr (AFFINE_A) { AFFW(SW, 0, (T) + 1, kofB_); LOAD_RA(SL, 0, kofL_); } \
    else { ISSUE_A(0, WS, kofL_); } \
    BAR(); \
    MFMA_Q(1, 1); \
    /* PH3 */ \
    if constexpr (AFFINE_A) { AFFW(SW, 1, (T) + 1, kofB_); LOAD_RA(SL, 1, kofL_); LGKM0; } \
    else { ISSUE_A(1, WS, kofL_); } \
    MFMA_Q(1, 0); \
    VMCNT(6); BAR(); \
}while(0)

    const int nkt = K >> 6;   // >= 8, even

    // ---- prologue ----
    if constexpr (AFFINE_A) {
        for (int i = tid; i < K; i += 512) {
            sm.f.ss[i] = scale[i]; sm.f.ss[1024 + i] = shift[i];
        }
        GLD_B(0, 0, 0); GLD_B(1, 0, 0);           // B(0) -> f.b[0]
        LOAD_RA(rAe, 0, 0); LOAD_RA(rAe, 1, 0);   // tile0
        LOAD_RA(rAo, 0, 64); LOAD_RA(rAo, 1, 64); // tile1 (stays in flight)
        LGKM0;        // ss stores drained (per-wave)
        BAR();        // ss visible to all waves
        AFFW(rAe, 0, 0, 0); AFFW(rAe, 1, 0, 0);   // A(0)->slot0 (auto vmcnt on rAe)
        LGKM0;        // A(0) ds_writes drained
        BAR();
    } else {
        GLD_B(0, 0, 0); GLD_B(1, 0, 0);
        ISSUE_A(0, 0, 0); ISSUE_A(1, 0, 0);       // tile0 -> slot0
        ISSUE_A(0, 1, 64); ISSUE_A(1, 1, 64);     // tile1 -> slot1
        VMCNT(0); BAR();
    }

    // ---- steady loop: nkt-2 iterations (even), 2-unrolled for rA set parity ----
    int rs = 0;
    for (int t = 0; t < nkt - 2; t += 2) {
        const int ws0 = (rs == 0) ? 2 : rs - 1;        // (rs+2)%3
        KSTEP(t, rs, ws0, rAo, rAe);                   // even t: write o, load e
        const int rs1 = (rs == 2) ? 0 : rs + 1;
        const int ws1 = (ws0 == 2) ? 0 : ws0 + 1;
        KSTEP(t + 1, rs1, ws1, rAe, rAo);              // odd t: write e, load o
        rs = (rs1 == 2) ? 0 : rs1 + 1;
    }

    // ---- peel t = nkt-2: no A issues; VMCNT(2) at END ----
    {
        const int T = nkt - 2;
        const int kofB_ = (T + 1) << 6;
        const u16* aR_ = ABASE(T, rs);
        const u16* bR_ = BRD(T);
        READ_A(aR_, 0); READ_B(bR_, 0);
        if constexpr (!AFFINE_A) LGKM0;
        VMCNT(4); BAR();
        GLD_B(0, T + 1, kofB_);
        MFMA_Q(0, 0);
        READ_B(bR_, 1);
        if constexpr (!AFFINE_A) LGKM0;
        BAR();
        GLD_B(1, T + 1, kofB_);
        MFMA_Q(0, 1);
        READ_A(aR_, 1);
        if constexpr (AFFINE_A) { AFFW(rAo, 0, T + 1, kofB_); }
        BAR();
        MFMA_Q(1, 1);
        if constexpr (AFFINE_A) { AFFW(rAo, 1, T + 1, kofB_); LGKM0; }
        MFMA_Q(1, 0);
        VMCNT(2); BAR();
    }
    // ---- peel t = nkt-1: final tile, drain to 0 ----
    {
        const int T = nkt - 1;
        const int rs2 = (rs == 2) ? 0 : rs + 1;
        const u16* aR_ = ABASE(T, rs2);
        const u16* bR_ = BRD(T);
        READ_A(aR_, 0); READ_B(bR_, 0);
        VMCNT(0); BAR();
        MFMA_Q(0, 0);
        READ_B(bR_, 1);
        MFMA_Q(0, 1);
        READ_A(aR_, 1);
        MFMA_Q(1, 1);
        MFMA_Q(1, 0);
        BAR();   // all waves' final ds_reads consumed before ep overlay writes
    }

    // ---- epilogue: C/D layout col=lane&15, row=(lane>>4)*4+reg ----
    const int cl = l15, quad = lane >> 4;
    if constexpr (OUT_F32) {
        UNROLL for (int j = 0; j < 4; j++) {
            const int col = bn * 256 + wn * 64 + j * 16 + cl;
            const float bcol = bias[col];
            UNROLL for (int i = 0; i < 8; i++) {
                const int r0 = bm * 256 + wm * 128 + i * 16 + quad * 4;
                UNROLL for (int r = 0; r < 4; r++)
                    ((float*)Cout)[(size_t)(r0 + r) * N + col] = acc[i][j][r] + bcol;
            }
        }
    } else {
        UNROLL for (int j = 0; j < 4; j++) {
            const int colL = wn * 64 + j * 16 + cl;
            const int col = bn * 256 + colL;
            float bcol = 0.f;
            if constexpr (!STATS) bcol = bias[col];
            float s = 0.f, ss2 = 0.f;
            UNROLL for (int i = 0; i < 8; i++) {
                const int rL0 = wm * 128 + i * 16 + quad * 4;
                UNROLL for (int r = 0; r < 4; r++) {
                    const float v = acc[i][j][r];
                    if constexpr (STATS) { s += v; ss2 += v * v; }
                    sm.ep[(rL0 + r) * EPW + colL] = f2b(v + bcol);
                }
            }
            if constexpr (STATS) {
                s   += __shfl_xor(s, 16);   s   += __shfl_xor(s, 32);
                ss2 += __shfl_xor(ss2, 16); ss2 += __shfl_xor(ss2, 32);
                if (quad == 0) { atomicAdd(&psum[col], s); atomicAdd(&psumsq[col], ss2); }
            }
        }
        __syncthreads();
        u16* Cb = (u16*)Cout;
        UNROLL for (int it = 0; it < 16; it++) {
            const int row = it * 16 + (tid >> 5);
            const int c8  = (tid & 31) * 8;
            const uint4 v = *(const uint4*)&sm.ep[row * EPW + c8];
            *(uint4*)(Cb + (size_t)(bm * 256 + row) * N + bn * 256 + c8) = v;
        }
    }
#undef ABASE
#undef BRD
#undef BSTG
#undef GLD_B
#undef ISSUE_A
#undef LOAD_RA
#undef AFFW
#undef READ_A
#undef READ_B
#undef MFMA_Q
#undef KSTEP
}

// ---------------- W (KxN fp32) -> WT (NxK bf16), tiled transpose ----------------
__global__ void cvt_transpose_w(const float* __restrict__ W, u16* __restrict__ WT, int K, int N) {
    __shared__ float t[32][33];
    const int tx = threadIdx.x, ty = threadIdx.y;
    const int n0 = blockIdx.x * 32, k0 = blockIdx.y * 32;
#pragma unroll
    for (int r = 0; r < 4; r++)
        t[ty + r * 8][tx] = W[(size_t)(k0 + ty + r * 8) * N + n0 + tx];
    __syncthreads();
#pragma unroll
    for (int r = 0; r < 4; r++)
        WT[(size_t)(n0 + ty + r * 8) * K + k0 + tx] = f2b(t[tx][ty + r * 8]);
}

// ---------------- fp32 -> bf16 elementwise (8 elems/thread) ----------------
__global__ void cvt_f32_bf16(const float* __restrict__ x, u16* __restrict__ y, long n8) {
    const long t = (long)blockIdx.x * 256 + threadIdx.x;
    if (t >= n8) return;
    const float4 a = ((const float4*)x)[t * 2];
    const float4 b = ((const float4*)x)[t * 2 + 1];
    union { uint4 u; u16 s[8]; } o;
    o.s[0] = f2b(a.x); o.s[1] = f2b(a.y); o.s[2] = f2b(a.z); o.s[3] = f2b(a.w);
    o.s[4] = f2b(b.x); o.s[5] = f2b(b.y); o.s[6] = f2b(b.z); o.s[7] = f2b(b.w);
    ((uint4*)y)[t] = o.u;
}

// ---------------- per-channel BN scale/shift from sums ----------------
__global__ void bn_finalize(const float* __restrict__ sum, const float* __restrict__ sumsq,
                            const float* __restrict__ g, const float* __restrict__ be,
                            float* __restrict__ scale, float* __restrict__ shift,
                            int Cc, float invM) {
    const int c = blockIdx.x * 256 + threadIdx.x;
    if (c >= Cc) return;
    const float mu = sum[c] * invM;
    const float var = fmaf(sumsq[c], invM, -mu * mu);
    const float sc = g[c] * rsqrtf(var + 1e-5f);
    scale[c] = sc;
    shift[c] = fmaf(-mu, sc, be[c]);
}

extern "C" void kernel_launch(void* const* d_in, const int* in_sizes, int n_in,
                              void* d_out, int out_size, void* d_ws, size_t ws_size,
                              hipStream_t stream) {
    const float* f0     = (const float*)d_in[0];
    const float* f1     = (const float*)d_in[1];
    const float* f2     = (const float*)d_in[2];
    const float* up0_w1 = (const float*)d_in[3];
    const float* up0_g  = (const float*)d_in[5];
    const float* up0_be = (const float*)d_in[6];
    const float* up0_w2 = (const float*)d_in[7];
    const float* up0_b2 = (const float*)d_in[8];
    const float* up1_w1 = (const float*)d_in[9];
    const float* up1_g  = (const float*)d_in[11];
    const float* up1_be = (const float*)d_in[12];
    const float* up1_w2 = (const float*)d_in[13];
    const float* up1_b2 = (const float*)d_in[14];
    const float* sk0_w1 = (const float*)d_in[15];
    const float* sk0_g  = (const float*)d_in[17];
    const float* sk0_be = (const float*)d_in[18];
    const float* sk0_w2 = (const float*)d_in[19];
    const float* sk0_b2 = (const float*)d_in[20];
    const float* sk1_w1 = (const float*)d_in[21];
    const float* sk1_g  = (const float*)d_in[23];
    const float* sk1_be = (const float*)d_in[24];
    const float* sk1_w2 = (const float*)d_in[25];
    const float* sk1_b2 = (const float*)d_in[26];
    const int* pool0    = (const int*)d_in[27];
    const int* pool1    = (const int*)d_in[28];
    float* out = (float*)d_out;

    char* ws = (char*)d_ws;
    size_t off = 0;
    auto alloc = [&](size_t bytes) -> void* {
        void* p = ws + off;
        off += (bytes + 255) & ~(size_t)255;
        return p;
    };
    u16* w_up1_1 = (u16*)alloc((size_t)1024 * 1024 * 2);
    u16* w_up1_2 = (u16*)alloc((size_t)512 * 1024 * 2);
    u16* w_sk1_1 = (u16*)alloc((size_t)1024 * 1024 * 2);
    u16* w_sk1_2 = (u16*)alloc((size_t)512 * 1024 * 2);
    u16* w_up0_1 = (u16*)alloc((size_t)512 * 512 * 2);
    u16* w_up0_2 = (u16*)alloc((size_t)256 * 512 * 2);
    u16* w_sk0_1 = (u16*)alloc((size_t)512 * 512 * 2);
    u16* w_sk0_2 = (u16*)alloc((size_t)256 * 512 * 2);
    float* stats = (float*)alloc((size_t)4 * 4096 * 4);    // per MLP: sum|sumsq|scale|shift
    u16* Hbuf    = (u16*)alloc((size_t)131072 * 512 * 2);  // 134 MB
    u16* Xbuf    = (u16*)alloc((size_t)32768 * 512 * 2);   // 33 MB
    u16* f0b     = (u16*)alloc((size_t)4 * 32768 * 256 * 2); // 67 MB
    u16* f1b     = (u16*)alloc((size_t)4 * 8192 * 512 * 2);  // 33 MB
    u16* f2b_    = (u16*)alloc((size_t)4 * 2048 * 1024 * 2); // 17 MB

    const dim3 tb(32, 8);
    cvt_transpose_w<<<dim3(32, 32), tb, 0, stream>>>(up1_w1, w_up1_1, 1024, 1024);
    cvt_transpose_w<<<dim3(16, 32), tb, 0, stream>>>(up1_w2, w_up1_2, 1024, 512);
    cvt_transpose_w<<<dim3(32, 32), tb, 0, stream>>>(sk1_w1, w_sk1_1, 1024, 1024);
    cvt_transpose_w<<<dim3(16, 32), tb, 0, stream>>>(sk1_w2, w_sk1_2, 1024, 512);
    cvt_transpose_w<<<dim3(16, 16), tb, 0, stream>>>(up0_w1, w_up0_1, 512, 512);
    cvt_transpose_w<<<dim3(8, 16),  tb, 0, stream>>>(up0_w2, w_up0_2, 512, 256);
    cvt_transpose_w<<<dim3(16, 16), tb, 0, stream>>>(sk0_w1, w_sk0_1, 512, 512);
    cvt_transpose_w<<<dim3(8, 16),  tb, 0, stream>>>(sk0_w2, w_sk0_2, 512, 256);

    hipMemsetAsync(stats, 0, (size_t)4 * 4096 * sizeof(float), stream);
    cvt_f32_bf16<<<4096,  256, 0, stream>>>(f2, f2b_, 8388608L / 8);
    cvt_f32_bf16<<<8192,  256, 0, stream>>>(f1, f1b, 16777216L / 8);
    cvt_f32_bf16<<<16384, 256, 0, stream>>>(f0, f0b, 33554432L / 8);

    float* st0 = stats;
    float* st1 = stats + 4096;
    float* st2 = stats + 8192;
    float* st3 = stats + 12288;

    // ---- up1: (8192x1024)@(1024x1024) -> BN -> ReLU -> @(1024x512) ----
    gemm_bn<false, true, false, false><<<dim3(4, 32), 512, 0, stream>>>(
        f2b_, w_up1_1, Hbuf, nullptr, nullptr, nullptr, st0, st0 + 1024,
        nullptr, nullptr, 0, 0, 0, 1024, 1024);
    bn_finalize<<<4, 256, 0, stream>>>(st0, st0 + 1024, up1_g, up1_be, st0 + 2048, st0 + 3072, 1024, 1.f / 8192.f);
    gemm_bn<true, false, false, false><<<dim3(2, 32), 512, 0, stream>>>(
        Hbuf, w_up1_2, Xbuf, st0 + 2048, st0 + 3072, up1_b2, nullptr, nullptr,
        nullptr, nullptr, 0, 0, 0, 512, 1024);

    // ---- skip1: concat[f1|gather(X,pool1)] (32768x1024) @ w -> BN -> ReLU -> @ w2 ----
    gemm_bn<false, true, false, true><<<dim3(4, 128), 512, 0, stream>>>(
        f1b, w_sk1_1, Hbuf, nullptr, nullptr, nullptr, st1, st1 + 1024,
        Xbuf, pool1, 13, 2048, 512, 1024, 1024);
    bn_finalize<<<4, 256, 0, stream>>>(st1, st1 + 1024, sk1_g, sk1_be, st1 + 2048, st1 + 3072, 1024, 1.f / 32768.f);
    gemm_bn<true, false, false, false><<<dim3(2, 128), 512, 0, stream>>>(
        Hbuf, w_sk1_2, Xbuf, st1 + 2048, st1 + 3072, sk1_b2, nullptr, nullptr,
        nullptr, nullptr, 0, 0, 0, 512, 1024);

    // ---- up0: (32768x512)@(512x512) -> BN -> ReLU -> @(512x256) ----
    gemm_bn<false, true, false, false><<<dim3(2, 128), 512, 0, stream>>>(
        Xbuf, w_up0_1, Hbuf, nullptr, nullptr, nullptr, st2, st2 + 1024,
        nullptr, nullptr, 0, 0, 0, 512, 512);
    bn_finalize<<<2, 256, 0, stream>>>(st2, st2 + 1024, up0_g, up0_be, st2 + 2048, st2 + 3072, 512, 1.f / 32768.f);
    gemm_bn<true, false, false, false><<<dim3(1, 128), 512, 0, stream>>>(
        Hbuf, w_up0_2, Xbuf, st2 + 2048, st2 + 3072, up0_b2, nullptr, nullptr,
        nullptr, nullptr, 0, 0, 0, 256, 512);

    // ---- skip0: concat[f0|gather(X,pool0)] (131072x512) @ w -> BN -> ReLU -> @ w2 -> fp32 ----
    gemm_bn<false, true, false, true><<<dim3(2, 512), 512, 0, stream>>>(
        f0b, w_sk0_1, Hbuf, nullptr, nullptr, nullptr, st3, st3 + 1024,
        Xbuf, pool0, 15, 8192, 256, 512, 512);
    bn_finalize<<<2, 256, 0, stream>>>(st3, st3 + 1024, sk0_g, sk0_be, st3 + 2048, st3 + 3072, 512, 1.f / 131072.f);
    gemm_bn<true, false, true, false><<<dim3(1, 512), 512, 0, stream>>>(
        Hbuf, w_sk0_2, out, st3 + 2048, st3 + 3072, sk0_b2, nullptr, nullptr,
        nullptr, nullptr, 0, 0, 0, 256, 512);
}

// Round 5
// 833.379 us; speedup vs baseline: 1.1474x; 1.1474x over previous
//
#include <hip/hip_runtime.h>

// FeatureDecoder: 4x (Linear -> BN(batch stats) -> ReLU -> Linear) with gathers.
// R7 = R6 resubmission (R6 bench died with the same infra signature as R3,
// which later passed verbatim as R4; both halves of R6 ran correctly on HW in
// prior rounds: AFFINE loop == R4's 831us kernel, non-AFFINE 3-slot loop ==
// R5's passing kernel).
//  - AFFINE path: R4 structure (1-ahead dbuf, single rA[2][2], lazy A-hi
//    ds_write at PH2, ledger VMCNT(6)/(6)/(4), peel (2)/(0)). No spill.
//  - non-AFFINE/GATHER: 2-deep A prefetch via 3-slot LDS rotation (zero VGPR
//    cost), single-slot B (L2-hot weights, 1-ahead; read-drain LGKM0 before
//    BAR + post-BAR issue). Ledger: steady VMCNT(4)@PH0, VMCNT(6)@PH3;
//    peel VMCNT(2)/(0). A-loads get ~6 phases (~1200cy) slack >= HBM latency.
// T2 swizzle (0 conflicts measured) + T5 setprio unchanged.

typedef unsigned short u16;
typedef __attribute__((ext_vector_type(8))) short bf16x8;
typedef __attribute__((ext_vector_type(4))) float f32x4;

#define UNROLL _Pragma("unroll")
#define EPW 264  // epilogue LDS row stride (u16)

__device__ __forceinline__ float b2f(u16 u) {
    union { unsigned int i; float f; } v; v.i = ((unsigned int)u) << 16; return v.f;
}
__device__ __forceinline__ u16 f2b(float f) {
    union { float f; unsigned int i; } v; v.f = f;
    unsigned int r = v.i + 0x7FFFu + ((v.i >> 16) & 1u);
    return (u16)(r >> 16);
}

__device__ __forceinline__ void gld_lds16(const u16* g, u16* l) {
    __builtin_amdgcn_global_load_lds(
        (const __attribute__((address_space(1))) unsigned int*)g,
        (__attribute__((address_space(3))) unsigned int*)l,
        16, 0, 0);
}

#define VMCNT(n) asm volatile("s_waitcnt vmcnt(" #n ")" ::: "memory")
#define LGKM0    asm volatile("s_waitcnt lgkmcnt(0)" ::: "memory")
#define BAR()    do{ asm volatile("" ::: "memory"); \
                     __builtin_amdgcn_s_barrier(); \
                     asm volatile("" ::: "memory"); }while(0)

union SMem {
    struct { u16 a[3][16384]; u16 b[16384]; } g;                      // 131072 B
    struct { u16 a[2][16384]; u16 b[2][16384]; float ss[2048]; } f;   // 139264 B
    u16 ep[256 * EPW];                                                 // 135168 B
};

// ---------------- GEMM: C(MxN) = A(MxK bf16) @ BT(NxK bf16)^T ----------------
template <bool AFFINE_A, bool STATS, bool OUT_F32, bool GATHER>
__global__ __launch_bounds__(512, 2) void gemm_bn(
    const u16* __restrict__ A, const u16* __restrict__ BT, void* __restrict__ Cout,
    const float* __restrict__ scale, const float* __restrict__ shift,
    const float* __restrict__ bias,
    float* __restrict__ psum, float* __restrict__ psumsq,
    const u16* __restrict__ Xg, const int* __restrict__ pool,
    int nfShift, int Nc, int Chalf,
    int N, int K)
{
    __shared__ __align__(16) SMem sm;

    const int tid  = threadIdx.x;
    const int w    = tid >> 6;
    const int lane = tid & 63;
    const int wm   = w >> 2, wn = w & 3;      // 2M x 4N waves; per-wave C = 128x64
    const int l15  = lane & 15;
    const int xorv = (lane & 7) << 3;          // read-side swizzle (row&7 == lane&7)
    const int swz8 = ((lane & 7) ^ (lane >> 3)) << 3;  // write-source swizzle chunk
    const int kS0  = (((lane >> 4) << 3)) ^ xorv;
    const int kS1  = (32 + ((lane >> 4) << 3)) ^ xorv;

    // XCD-aware bijective swizzle (all grids are %8==0): contiguous chunk per XCD.
    int bm, bn;
    {
        const int nbn  = (int)gridDim.x;
        const int nwg  = nbn * (int)gridDim.y;
        const int flat = (int)(blockIdx.y * gridDim.x + blockIdx.x);
        const int wg   = (flat & 7) * (nwg >> 3) + (flat >> 3);
        const int lb   = 31 - __builtin_clz(nbn);
        bn = wg & (nbn - 1);
        bm = wg >> lb;
    }

    // ---- staging source/dest setup ----
    const u16* aS[2][2]; const u16* xS[2][2]; const u16* bS[2][2];
    int dA[2][2], dB[2][2], wIdx[2][2];
    UNROLL for (int u = 0; u < 2; u++)
    UNROLL for (int ld = 0; ld < 2; ld++) {
        const int urb = w * 16 + ld * 8;          // wave-uniform 8-row chunk base
        const int ur  = urb + (lane >> 3);        // per-lane unit-row
        {
            const int trb = urb + (urb >= 64 ? 64 : 0) + u * 64;
            const int tr  = ur  + (ur  >= 64 ? 64 : 0) + u * 64;
            dA[u][ld] = trb * 64;
            const int rowG = bm * 256 + tr;
            if constexpr (GATHER) {
                const int b = rowG >> nfShift;
                const int p = pool[rowG];
                aS[u][ld] = A  + (size_t)rowG * Chalf + swz8;
                xS[u][ld] = Xg + ((size_t)b * Nc + p) * Chalf + swz8;
            } else if constexpr (AFFINE_A) {
                aS[u][ld] = A + (size_t)rowG * K + ((lane & 7) << 3);  // linear src
                wIdx[u][ld] = tr * 64 + swz8;                          // swizzled dst
            } else {
                aS[u][ld] = A + (size_t)rowG * K + swz8;
            }
        }
        {
            const int trb = ((urb >> 5) << 6) + (urb & 31) + u * 32;
            const int tr  = ((ur  >> 5) << 6) + (ur  & 31) + u * 32;
            dB[u][ld] = trb * 64;
            bS[u][ld] = BT + (size_t)(bn * 256 + tr) * K + swz8;
        }
    }

    f32x4 acc[8][4];
    const f32x4 zero = {0.f, 0.f, 0.f, 0.f};
    UNROLL for (int i = 0; i < 8; i++)
    UNROLL for (int j = 0; j < 4; j++) acc[i][j] = zero;
    bf16x8 afr[4][2];
    bf16x8 bfr[2][2][2];
    uint4 rA[2][2];   // AFFINE in-flight A regs (DCE'd otherwise)

#define GLD_B(u, BASE, KOF) do{ \
    u16* bt_ = (BASE); \
    gld_lds16(bS[u][0] + (KOF), bt_ + dB[u][0]); \
    gld_lds16(bS[u][1] + (KOF), bt_ + dB[u][1]); }while(0)

#define ISSUE_A(u, BASE, KOF) do{ \
    u16* at_ = (BASE); \
    if constexpr (GATHER) { \
        const u16 *s0_, *s1_; \
        if ((KOF) < Chalf) { s0_ = aS[u][0] + (KOF); s1_ = aS[u][1] + (KOF); } \
        else { s0_ = xS[u][0] + ((KOF) - Chalf); s1_ = xS[u][1] + ((KOF) - Chalf); } \
        gld_lds16(s0_, at_ + dA[u][0]); \
        gld_lds16(s1_, at_ + dA[u][1]); \
    } else { \
        gld_lds16(aS[u][0] + (KOF), at_ + dA[u][0]); \
        gld_lds16(aS[u][1] + (KOF), at_ + dA[u][1]); \
    } }while(0)

#define LOAD_RA(u, KOF) do{ \
    rA[u][0] = *(const uint4*)(aS[u][0] + (KOF)); \
    rA[u][1] = *(const uint4*)(aS[u][1] + (KOF)); }while(0)

#define AFFW(u, BASE, KOF) do{ if constexpr (AFFINE_A) { \
    u16* at_ = (BASE); \
    const int kb_ = (KOF) + ((lane & 7) << 3); \
    const float4 sc0_ = *(const float4*)&sm.f.ss[kb_]; \
    const float4 sc1_ = *(const float4*)&sm.f.ss[kb_ + 4]; \
    const float4 sh0_ = *(const float4*)&sm.f.ss[1024 + kb_]; \
    const float4 sh1_ = *(const float4*)&sm.f.ss[1024 + kb_ + 4]; \
    UNROLL for (int ld_ = 0; ld_ < 2; ld_++) { \
        union { uint4 u4; u16 s[8]; } r_, o_; r_.u4 = rA[u][ld_]; \
        o_.s[0] = f2b(fmaxf(b2f(r_.s[0]) * sc0_.x + sh0_.x, 0.f)); \
        o_.s[1] = f2b(fmaxf(b2f(r_.s[1]) * sc0_.y + sh0_.y, 0.f)); \
        o_.s[2] = f2b(fmaxf(b2f(r_.s[2]) * sc0_.z + sh0_.z, 0.f)); \
        o_.s[3] = f2b(fmaxf(b2f(r_.s[3]) * sc0_.w + sh0_.w, 0.f)); \
        o_.s[4] = f2b(fmaxf(b2f(r_.s[4]) * sc1_.x + sh1_.x, 0.f)); \
        o_.s[5] = f2b(fmaxf(b2f(r_.s[5]) * sc1_.y + sh1_.y, 0.f)); \
        o_.s[6] = f2b(fmaxf(b2f(r_.s[6]) * sc1_.z + sh1_.z, 0.f)); \
        o_.s[7] = f2b(fmaxf(b2f(r_.s[7]) * sc1_.w + sh1_.w, 0.f)); \
        *(uint4*)&at_[wIdx[u][ld_]] = o_.u4; } \
    LGKM0; } }while(0)

#define READ_A(base, qi) do{ const u16* p_ = (base); \
    UNROLL for (int i_ = 0; i_ < 4; i_++) { \
        const int rb_ = (wm * 128 + ((qi) * 4 + i_) * 16 + l15) * 64; \
        afr[i_][0] = *(const bf16x8*)&p_[rb_ + kS0]; \
        afr[i_][1] = *(const bf16x8*)&p_[rb_ + kS1]; } }while(0)

#define READ_B(base, qj) do{ const u16* p_ = (base); \
    UNROLL for (int j_ = 0; j_ < 2; j_++) { \
        const int rb_ = (wn * 64 + ((qj) * 2 + j_) * 16 + l15) * 64; \
        bfr[qj][j_][0] = *(const bf16x8*)&p_[rb_ + kS0]; \
        bfr[qj][j_][1] = *(const bf16x8*)&p_[rb_ + kS1]; } }while(0)

#define MFMA_Q(qi, qj) do{ __builtin_amdgcn_s_setprio(1); \
    UNROLL for (int i_ = 0; i_ < 4; i_++) \
    UNROLL for (int j_ = 0; j_ < 2; j_++) { \
        acc[(qi)*4+i_][(qj)*2+j_] = __builtin_amdgcn_mfma_f32_16x16x32_bf16( \
            afr[i_][0], bfr[qj][j_][0], acc[(qi)*4+i_][(qj)*2+j_], 0, 0, 0); \
        acc[(qi)*4+i_][(qj)*2+j_] = __builtin_amdgcn_mfma_f32_16x16x32_bf16( \
            afr[i_][1], bfr[qj][j_][1], acc[(qi)*4+i_][(qj)*2+j_], 0, 0, 0); } \
    __builtin_amdgcn_s_setprio(0); }while(0)

    const int nkt = K >> 6;   // >= 8

    if constexpr (AFFINE_A) {
        // ================= AFFINE: R4 structure (proven, no spill) =============
        for (int i = tid; i < K; i += 512) {
            sm.f.ss[i] = scale[i]; sm.f.ss[1024 + i] = shift[i];
        }
        LOAD_RA(0, 0);
        GLD_B(0, &sm.f.b[0][0], 0); GLD_B(1, &sm.f.b[0][0], 0);
        LOAD_RA(1, 0);
        asm volatile("s_waitcnt vmcnt(0) lgkmcnt(0)" ::: "memory");
        BAR();
        AFFW(0, &sm.f.a[0][0], 0);    // A-lo(0) -> slot0 (AFFW ends with LGKM0)
        BAR();

        for (int t = 0; t < nkt - 1; ++t) {
            const int buf = t & 1, nb = buf ^ 1;
            const int kofN = (t + 1) << 6;
            u16* aB = &sm.f.a[buf][0]; u16* aN = &sm.f.a[nb][0];
            u16* bB = &sm.f.b[buf][0]; u16* bN = &sm.f.b[nb][0];
            // PH0
            LOAD_RA(0, kofN);
            READ_A(aB, 0); READ_B(bB, 0);
            BAR();
            MFMA_Q(0, 0);
            // PH1 (VMCNT(6) confirms B1(t))
            GLD_B(0, bN, kofN);
            VMCNT(6); BAR();
            READ_B(bB, 1);
            MFMA_Q(0, 1);
            // PH2 (lazy A-hi(t) write, consumed after this BAR)
            GLD_B(1, bN, kofN);
            VMCNT(6);
            AFFW(1, aB, t << 6);
            BAR();
            READ_A(aB, 1);
            MFMA_Q(1, 1);
            // PH3 (VMCNT(4) confirms rA0(t+1)+B0(t+1))
            LOAD_RA(1, kofN);
            MFMA_Q(1, 0);
            VMCNT(4);
            AFFW(0, aN, kofN);
            BAR();
        }
        {   // peel t = nkt-1
            const int t = nkt - 1, buf = t & 1;
            u16* aB = &sm.f.a[buf][0]; u16* bB = &sm.f.b[buf][0];
            READ_A(aB, 0); READ_B(bB, 0);
            BAR();
            MFMA_Q(0, 0);
            VMCNT(2); BAR();
            READ_B(bB, 1);
            MFMA_Q(0, 1);
            VMCNT(0);
            AFFW(1, aB, t << 6);
            BAR();
            READ_A(aB, 1);
            MFMA_Q(1, 1);
            BAR();
            MFMA_Q(1, 0);
        }
    } else {
        // ======= non-AFFINE/GATHER: 3-slot A (2-ahead), 1-slot B (1-ahead) ====
        u16* const bb = &sm.g.b[0];
        GLD_B(0, bb, 0); GLD_B(1, bb, 0);
        ISSUE_A(0, &sm.g.a[0][0], 0);  ISSUE_A(1, &sm.g.a[0][0], 0);
        ISSUE_A(0, &sm.g.a[1][0], 64); ISSUE_A(1, &sm.g.a[1][0], 64);
        VMCNT(0); BAR();

        int rs = 0;
        for (int t = 0; t < nkt - 2; ++t) {
            const int ws = (rs == 0) ? 2 : rs - 1;       // (rs+2)%3
            const int kofB = (t + 1) << 6, kofL = (t + 2) << 6;
            const u16* aR = &sm.g.a[0][0] + rs * 16384;
            u16* aW = &sm.g.a[0][0] + ws * 16384;
            // PH0 (VMCNT(4): confirms B1(t); LGKM0: drain b-u0 reads pre-overwrite)
            READ_A(aR, 0); READ_B(bb, 0);
            LGKM0; VMCNT(4); BAR();
            GLD_B(0, bb, kofB);
            MFMA_Q(0, 0);
            // PH1
            READ_B(bb, 1);
            LGKM0; BAR();
            GLD_B(1, bb, kofB);
            MFMA_Q(0, 1);
            // PH2 (issue A(t+2) into write slot)
            READ_A(aR, 1);
            ISSUE_A(0, aW, kofL);
            BAR();
            MFMA_Q(1, 1);
            // PH3 (VMCNT(6): confirms A0(t+1),A1(t+1),B0(t+1))
            ISSUE_A(1, aW, kofL);
            MFMA_Q(1, 0);
            VMCNT(6); BAR();
            rs = (rs == 2) ? 0 : rs + 1;
        }
        {   // peel t = nkt-2: no A issues; VMCNT(2) at END confirms A(t+1)+B0(t+1)
            const int t = nkt - 2;
            const int kofB = (t + 1) << 6;
            const u16* aR = &sm.g.a[0][0] + rs * 16384;
            READ_A(aR, 0); READ_B(bb, 0);
            LGKM0; VMCNT(4); BAR();
            GLD_B(0, bb, kofB);
            MFMA_Q(0, 0);
            READ_B(bb, 1);
            LGKM0; BAR();
            GLD_B(1, bb, kofB);
            MFMA_Q(0, 1);
            READ_A(aR, 1);
            BAR();
            MFMA_Q(1, 1);
            MFMA_Q(1, 0);
            VMCNT(2); BAR();
            rs = (rs == 2) ? 0 : rs + 1;
        }
        {   // peel t = nkt-1: final tile, drain
            const u16* aR = &sm.g.a[0][0] + rs * 16384;
            READ_A(aR, 0); READ_B(bb, 0);
            VMCNT(0); BAR();
            MFMA_Q(0, 0);
            READ_B(bb, 1);
            MFMA_Q(0, 1);
            READ_A(aR, 1);
            MFMA_Q(1, 1);
            MFMA_Q(1, 0);
            LGKM0; BAR();
        }
    }

    // ---- epilogue: C/D layout col=lane&15, row=(lane>>4)*4+reg ----
    const int cl = l15, quad = lane >> 4;
    if constexpr (OUT_F32) {
        UNROLL for (int j = 0; j < 4; j++) {
            const int col = bn * 256 + wn * 64 + j * 16 + cl;
            const float bcol = bias[col];
            UNROLL for (int i = 0; i < 8; i++) {
                const int r0 = bm * 256 + wm * 128 + i * 16 + quad * 4;
                UNROLL for (int r = 0; r < 4; r++)
                    ((float*)Cout)[(size_t)(r0 + r) * N + col] = acc[i][j][r] + bcol;
            }
        }
    } else {
        UNROLL for (int j = 0; j < 4; j++) {
            const int colL = wn * 64 + j * 16 + cl;
            const int col = bn * 256 + colL;
            float bcol = 0.f;
            if constexpr (!STATS) bcol = bias[col];
            float s = 0.f, ss2 = 0.f;
            UNROLL for (int i = 0; i < 8; i++) {
                const int rL0 = wm * 128 + i * 16 + quad * 4;
                UNROLL for (int r = 0; r < 4; r++) {
                    const float v = acc[i][j][r];
                    if constexpr (STATS) { s += v; ss2 += v * v; }
                    sm.ep[(rL0 + r) * EPW + colL] = f2b(v + bcol);
                }
            }
            if constexpr (STATS) {
                s   += __shfl_xor(s, 16);   s   += __shfl_xor(s, 32);
                ss2 += __shfl_xor(ss2, 16); ss2 += __shfl_xor(ss2, 32);
                if (quad == 0) { atomicAdd(&psum[col], s); atomicAdd(&psumsq[col], ss2); }
            }
        }
        __syncthreads();
        u16* Cb = (u16*)Cout;
        UNROLL for (int it = 0; it < 16; it++) {
            const int row = it * 16 + (tid >> 5);
            const int c8  = (tid & 31) * 8;
            const uint4 v = *(const uint4*)&sm.ep[row * EPW + c8];
            *(uint4*)(Cb + (size_t)(bm * 256 + row) * N + bn * 256 + c8) = v;
        }
    }
#undef GLD_B
#undef ISSUE_A
#undef LOAD_RA
#undef AFFW
#undef READ_A
#undef READ_B
#undef MFMA_Q
}

// ---------------- W (KxN fp32) -> WT (NxK bf16), tiled transpose ----------------
__global__ void cvt_transpose_w(const float* __restrict__ W, u16* __restrict__ WT, int K, int N) {
    __shared__ float t[32][33];
    const int tx = threadIdx.x, ty = threadIdx.y;
    const int n0 = blockIdx.x * 32, k0 = blockIdx.y * 32;
#pragma unroll
    for (int r = 0; r < 4; r++)
        t[ty + r * 8][tx] = W[(size_t)(k0 + ty + r * 8) * N + n0 + tx];
    __syncthreads();
#pragma unroll
    for (int r = 0; r < 4; r++)
        WT[(size_t)(n0 + ty + r * 8) * K + k0 + tx] = f2b(t[tx][ty + r * 8]);
}

// ---------------- fp32 -> bf16 elementwise (8 elems/thread) ----------------
__global__ void cvt_f32_bf16(const float* __restrict__ x, u16* __restrict__ y, long n8) {
    const long t = (long)blockIdx.x * 256 + threadIdx.x;
    if (t >= n8) return;
    const float4 a = ((const float4*)x)[t * 2];
    const float4 b = ((const float4*)x)[t * 2 + 1];
    union { uint4 u; u16 s[8]; } o;
    o.s[0] = f2b(a.x); o.s[1] = f2b(a.y); o.s[2] = f2b(a.z); o.s[3] = f2b(a.w);
    o.s[4] = f2b(b.x); o.s[5] = f2b(b.y); o.s[6] = f2b(b.z); o.s[7] = f2b(b.w);
    ((uint4*)y)[t] = o.u;
}

// ---------------- per-channel BN scale/shift from sums ----------------
__global__ void bn_finalize(const float* __restrict__ sum, const float* __restrict__ sumsq,
                            const float* __restrict__ g, const float* __restrict__ be,
                            float* __restrict__ scale, float* __restrict__ shift,
                            int Cc, float invM) {
    const int c = blockIdx.x * 256 + threadIdx.x;
    if (c >= Cc) return;
    const float mu = sum[c] * invM;
    const float var = fmaf(sumsq[c], invM, -mu * mu);
    const float sc = g[c] * rsqrtf(var + 1e-5f);
    scale[c] = sc;
    shift[c] = fmaf(-mu, sc, be[c]);
}

extern "C" void kernel_launch(void* const* d_in, const int* in_sizes, int n_in,
                              void* d_out, int out_size, void* d_ws, size_t ws_size,
                              hipStream_t stream) {
    const float* f0     = (const float*)d_in[0];
    const float* f1     = (const float*)d_in[1];
    const float* f2     = (const float*)d_in[2];
    const float* up0_w1 = (const float*)d_in[3];
    const float* up0_g  = (const float*)d_in[5];
    const float* up0_be = (const float*)d_in[6];
    const float* up0_w2 = (const float*)d_in[7];
    const float* up0_b2 = (const float*)d_in[8];
    const float* up1_w1 = (const float*)d_in[9];
    const float* up1_g  = (const float*)d_in[11];
    const float* up1_be = (const float*)d_in[12];
    const float* up1_w2 = (const float*)d_in[13];
    const float* up1_b2 = (const float*)d_in[14];
    const float* sk0_w1 = (const float*)d_in[15];
    const float* sk0_g  = (const float*)d_in[17];
    const float* sk0_be = (const float*)d_in[18];
    const float* sk0_w2 = (const float*)d_in[19];
    const float* sk0_b2 = (const float*)d_in[20];
    const float* sk1_w1 = (const float*)d_in[21];
    const float* sk1_g  = (const float*)d_in[23];
    const float* sk1_be = (const float*)d_in[24];
    const float* sk1_w2 = (const float*)d_in[25];
    const float* sk1_b2 = (const float*)d_in[26];
    const int* pool0    = (const int*)d_in[27];
    const int* pool1    = (const int*)d_in[28];
    float* out = (float*)d_out;

    char* ws = (char*)d_ws;
    size_t off = 0;
    auto alloc = [&](size_t bytes) -> void* {
        void* p = ws + off;
        off += (bytes + 255) & ~(size_t)255;
        return p;
    };
    u16* w_up1_1 = (u16*)alloc((size_t)1024 * 1024 * 2);
    u16* w_up1_2 = (u16*)alloc((size_t)512 * 1024 * 2);
    u16* w_sk1_1 = (u16*)alloc((size_t)1024 * 1024 * 2);
    u16* w_sk1_2 = (u16*)alloc((size_t)512 * 1024 * 2);
    u16* w_up0_1 = (u16*)alloc((size_t)512 * 512 * 2);
    u16* w_up0_2 = (u16*)alloc((size_t)256 * 512 * 2);
    u16* w_sk0_1 = (u16*)alloc((size_t)512 * 512 * 2);
    u16* w_sk0_2 = (u16*)alloc((size_t)256 * 512 * 2);
    float* stats = (float*)alloc((size_t)4 * 4096 * 4);    // per MLP: sum|sumsq|scale|shift
    u16* Hbuf    = (u16*)alloc((size_t)131072 * 512 * 2);  // 134 MB
    u16* Xbuf    = (u16*)alloc((size_t)32768 * 512 * 2);   // 33 MB
    u16* f0b     = (u16*)alloc((size_t)4 * 32768 * 256 * 2); // 67 MB
    u16* f1b     = (u16*)alloc((size_t)4 * 8192 * 512 * 2);  // 33 MB
    u16* f2b_    = (u16*)alloc((size_t)4 * 2048 * 1024 * 2); // 17 MB

    const dim3 tb(32, 8);
    cvt_transpose_w<<<dim3(32, 32), tb, 0, stream>>>(up1_w1, w_up1_1, 1024, 1024);
    cvt_transpose_w<<<dim3(16, 32), tb, 0, stream>>>(up1_w2, w_up1_2, 1024, 512);
    cvt_transpose_w<<<dim3(32, 32), tb, 0, stream>>>(sk1_w1, w_sk1_1, 1024, 1024);
    cvt_transpose_w<<<dim3(16, 32), tb, 0, stream>>>(sk1_w2, w_sk1_2, 1024, 512);
    cvt_transpose_w<<<dim3(16, 16), tb, 0, stream>>>(up0_w1, w_up0_1, 512, 512);
    cvt_transpose_w<<<dim3(8, 16),  tb, 0, stream>>>(up0_w2, w_up0_2, 512, 256);
    cvt_transpose_w<<<dim3(16, 16), tb, 0, stream>>>(sk0_w1, w_sk0_1, 512, 512);
    cvt_transpose_w<<<dim3(8, 16),  tb, 0, stream>>>(sk0_w2, w_sk0_2, 512, 256);

    hipMemsetAsync(stats, 0, (size_t)4 * 4096 * sizeof(float), stream);
    cvt_f32_bf16<<<4096,  256, 0, stream>>>(f2, f2b_, 8388608L / 8);
    cvt_f32_bf16<<<8192,  256, 0, stream>>>(f1, f1b, 16777216L / 8);
    cvt_f32_bf16<<<16384, 256, 0, stream>>>(f0, f0b, 33554432L / 8);

    float* st0 = stats;
    float* st1 = stats + 4096;
    float* st2 = stats + 8192;
    float* st3 = stats + 12288;

    // ---- up1: (8192x1024)@(1024x1024) -> BN -> ReLU -> @(1024x512) ----
    gemm_bn<false, true, false, false><<<dim3(4, 32), 512, 0, stream>>>(
        f2b_, w_up1_1, Hbuf, nullptr, nullptr, nullptr, st0, st0 + 1024,
        nullptr, nullptr, 0, 0, 0, 1024, 1024);
    bn_finalize<<<4, 256, 0, stream>>>(st0, st0 + 1024, up1_g, up1_be, st0 + 2048, st0 + 3072, 1024, 1.f / 8192.f);
    gemm_bn<true, false, false, false><<<dim3(2, 32), 512, 0, stream>>>(
        Hbuf, w_up1_2, Xbuf, st0 + 2048, st0 + 3072, up1_b2, nullptr, nullptr,
        nullptr, nullptr, 0, 0, 0, 512, 1024);

    // ---- skip1: concat[f1|gather(X,pool1)] (32768x1024) @ w -> BN -> ReLU -> @ w2 ----
    gemm_bn<false, true, false, true><<<dim3(4, 128), 512, 0, stream>>>(
        f1b, w_sk1_1, Hbuf, nullptr, nullptr, nullptr, st1, st1 + 1024,
        Xbuf, pool1, 13, 2048, 512, 1024, 1024);
    bn_finalize<<<4, 256, 0, stream>>>(st1, st1 + 1024, sk1_g, sk1_be, st1 + 2048, st1 + 3072, 1024, 1.f / 32768.f);
    gemm_bn<true, false, false, false><<<dim3(2, 128), 512, 0, stream>>>(
        Hbuf, w_sk1_2, Xbuf, st1 + 2048, st1 + 3072, sk1_b2, nullptr, nullptr,
        nullptr, nullptr, 0, 0, 0, 512, 1024);

    // ---- up0: (32768x512)@(512x512) -> BN -> ReLU -> @(512x256) ----
    gemm_bn<false, true, false, false><<<dim3(2, 128), 512, 0, stream>>>(
        Xbuf, w_up0_1, Hbuf, nullptr, nullptr, nullptr, st2, st2 + 1024,
        nullptr, nullptr, 0, 0, 0, 512, 512);
    bn_finalize<<<2, 256, 0, stream>>>(st2, st2 + 1024, up0_g, up0_be, st2 + 2048, st2 + 3072, 512, 1.f / 32768.f);
    gemm_bn<true, false, false, false><<<dim3(1, 128), 512, 0, stream>>>(
        Hbuf, w_up0_2, Xbuf, st2 + 2048, st2 + 3072, up0_b2, nullptr, nullptr,
        nullptr, nullptr, 0, 0, 0, 256, 512);

    // ---- skip0: concat[f0|gather(X,pool0)] (131072x512) @ w -> BN -> ReLU -> @ w2 -> fp32 ----
    gemm_bn<false, true, false, true><<<dim3(2, 512), 512, 0, stream>>>(
        f0b, w_sk0_1, Hbuf, nullptr, nullptr, nullptr, st3, st3 + 1024,
        Xbuf, pool0, 15, 8192, 256, 512, 512);
    bn_finalize<<<2, 256, 0, stream>>>(st3, st3 + 1024, sk0_g, sk0_be, st3 + 2048, st3 + 3072, 512, 1.f / 131072.f);
    gemm_bn<true, false, true, false><<<dim3(1, 512), 512, 0, stream>>>(
        Hbuf, w_sk0_2, out, st3 + 2048, st3 + 3072, sk0_b2, nullptr, nullptr,
        nullptr, nullptr, 0, 0, 0, 256, 512);
}